// Round 3
// baseline (796.191 us; speedup 1.0000x reference)
//
#include <hip/hip_runtime.h>

// GraphConvolution: out = segment_sum_dst( w_e * (x @ W)[src_e] )
// N=100000 nodes, E=3200000 edges, D_IN=256, D_OUT=128, fp32 in/out.
// support stored bf16x2. Edge records packed to 4B: w10 | local5 | src17.
// CSR built via localized two-phase scatter (bucket bin -> per-node sort).

#define DIN 256
#define DOUT 128
#define BUCKET_SHIFT 5
#define BUCKET_NODES 32

__device__ __forceinline__ unsigned pack_bf16x2(float a, float b) {
  unsigned ua = __float_as_uint(a);
  unsigned ub = __float_as_uint(b);
  ua += 0x7fffu + ((ua >> 16) & 1u);   // round-to-nearest-even
  ub += 0x7fffu + ((ub >> 16) & 1u);
  return (ua >> 16) | (ub & 0xffff0000u);
}
__device__ __forceinline__ float bf_lo(unsigned p) { return __uint_as_float(p << 16); }
__device__ __forceinline__ float bf_hi(unsigned p) { return __uint_as_float(p & 0xffff0000u); }

// ---------------- GEMM: support = x @ W (fp32 vector ALU, bf16x2 output) ---
__global__ __launch_bounds__(256) void gemm_kernel(const float* __restrict__ x,
                                                   const float* __restrict__ W,
                                                   unsigned* __restrict__ support,
                                                   int M) {
  __shared__ float As[64][33];
  __shared__ float Bs[32][132];
  const int tid = threadIdx.x;
  const int ty = tid >> 4;
  const int tx = tid & 15;
  const int rowBase = blockIdx.x * 64;

  float acc[4][8];
#pragma unroll
  for (int i = 0; i < 4; i++)
#pragma unroll
    for (int j = 0; j < 8; j++) acc[i][j] = 0.f;

  for (int k0 = 0; k0 < DIN; k0 += 32) {
#pragma unroll
    for (int l = 0; l < 2; l++) {
      int f = tid + l * 256;
      int r = f >> 3, c4 = f & 7;
      float4 v = make_float4(0.f, 0.f, 0.f, 0.f);
      int gr = rowBase + r;
      if (gr < M) v = *(const float4*)&x[(size_t)gr * DIN + k0 + c4 * 4];
      As[r][c4 * 4 + 0] = v.x; As[r][c4 * 4 + 1] = v.y;
      As[r][c4 * 4 + 2] = v.z; As[r][c4 * 4 + 3] = v.w;
    }
#pragma unroll
    for (int l = 0; l < 4; l++) {
      int f = tid + l * 256;
      int r = f >> 5, c4 = f & 31;
      float4 v = *(const float4*)&W[(size_t)(k0 + r) * DOUT + c4 * 4];
      *(float4*)&Bs[r][c4 * 4] = v;
    }
    __syncthreads();
#pragma unroll
    for (int kk = 0; kk < 32; kk++) {
      float a[4];
#pragma unroll
      for (int i = 0; i < 4; i++) a[i] = As[ty + i * 16][kk];
      float b[8];
#pragma unroll
      for (int jj = 0; jj < 4; jj++) {
        float2 bb = *(const float2*)&Bs[kk][32 * jj + 2 * tx];
        b[2 * jj] = bb.x; b[2 * jj + 1] = bb.y;
      }
#pragma unroll
      for (int i = 0; i < 4; i++)
#pragma unroll
        for (int j = 0; j < 8; j++) acc[i][j] += a[i] * b[j];
    }
    __syncthreads();
  }
#pragma unroll
  for (int i = 0; i < 4; i++) {
    int gr = rowBase + ty + i * 16;
    if (gr < M) {
#pragma unroll
      for (int jj = 0; jj < 4; jj++)
        support[(size_t)gr * 64 + 16 * jj + tx] =
            pack_bf16x2(acc[i][2 * jj], acc[i][2 * jj + 1]);
    }
  }
}

// ---------------- degree histogram (int4-vectorized) ----------------
__global__ void hist_kernel(const int* __restrict__ dst, int E, int* __restrict__ deg) {
  int i = blockIdx.x * blockDim.x + threadIdx.x;
  int e = i * 4;
  if (e + 3 < E) {
    int4 d = *(const int4*)&dst[e];
    atomicAdd(&deg[d.x], 1);
    atomicAdd(&deg[d.y], 1);
    atomicAdd(&deg[d.z], 1);
    atomicAdd(&deg[d.w], 1);
  } else {
    for (; e < E; e++) atomicAdd(&deg[dst[e]], 1);
  }
}

// ---------------- scan: deg -> row_ptr (+ bucket cursors) ----------------
__global__ __launch_bounds__(256) void scan1_kernel(const int* __restrict__ deg, int N,
                                                    int* __restrict__ tmp,
                                                    int* __restrict__ partials) {
  __shared__ int s[256];
  int t = threadIdx.x;
  int base = blockIdx.x * 1024 + t * 4;
  int d0 = 0, d1 = 0, d2 = 0, d3 = 0;
  if (base + 0 < N) d0 = deg[base + 0];
  if (base + 1 < N) d1 = deg[base + 1];
  if (base + 2 < N) d2 = deg[base + 2];
  if (base + 3 < N) d3 = deg[base + 3];
  int tsum = d0 + d1 + d2 + d3;
  s[t] = tsum;
  __syncthreads();
  for (int off = 1; off < 256; off <<= 1) {
    int v = (t >= off) ? s[t - off] : 0;
    __syncthreads();
    s[t] += v;
    __syncthreads();
  }
  int excl = s[t] - tsum;
  if (base + 0 < N) tmp[base + 0] = excl;
  excl += d0;
  if (base + 1 < N) tmp[base + 1] = excl;
  excl += d1;
  if (base + 2 < N) tmp[base + 2] = excl;
  excl += d2;
  if (base + 3 < N) tmp[base + 3] = excl;
  if (t == 255) partials[blockIdx.x] = s[255];
}

__global__ __launch_bounds__(128) void scan2_kernel(int* __restrict__ partials, int nb) {
  __shared__ int s[128];
  int t = threadIdx.x;
  int v = (t < nb) ? partials[t] : 0;
  s[t] = v;
  __syncthreads();
  for (int off = 1; off < 128; off <<= 1) {
    int u = (t >= off) ? s[t - off] : 0;
    __syncthreads();
    s[t] += u;
    __syncthreads();
  }
  if (t < nb) partials[t] = s[t] - v;
}

__global__ void scan3_kernel(const int* __restrict__ tmp, const int* __restrict__ partials,
                             int N, int E, int* __restrict__ row_ptr,
                             int* __restrict__ bcur) {
  int i = blockIdx.x * blockDim.x + threadIdx.x;
  if (i < N) {
    int v = tmp[i] + partials[i >> 10];
    row_ptr[i] = v;
    if ((i & (BUCKET_NODES - 1)) == 0) bcur[i >> BUCKET_SHIFT] = v;
  }
  if (i == 0) row_ptr[N] = E;
}

// ---------------- phase 1: bin edges by bucket (localized append) ----------
// record = w10<<22 | local5<<17 | src17
__device__ __forceinline__ unsigned pack_rec(int src, int local, float w) {
  unsigned wq = (unsigned)(w * 1024.f + 0.5f);
  if (wq > 1023u) wq = 1023u;
  return (wq << 22) | ((unsigned)local << 17) | (unsigned)src;
}

__global__ void bin_kernel(const int* __restrict__ src, const int* __restrict__ dst,
                           const float* __restrict__ w, int E,
                           int* __restrict__ bcur, unsigned* __restrict__ bin) {
  int i = blockIdx.x * blockDim.x + threadIdx.x;
  int e = i * 4;
  if (e + 3 < E) {
    int4 s4 = *(const int4*)&src[e];
    int4 d4 = *(const int4*)&dst[e];
    float4 w4 = *(const float4*)&w[e];
    int p0 = atomicAdd(&bcur[d4.x >> BUCKET_SHIFT], 1);
    int p1 = atomicAdd(&bcur[d4.y >> BUCKET_SHIFT], 1);
    int p2 = atomicAdd(&bcur[d4.z >> BUCKET_SHIFT], 1);
    int p3 = atomicAdd(&bcur[d4.w >> BUCKET_SHIFT], 1);
    bin[p0] = pack_rec(s4.x, d4.x & (BUCKET_NODES - 1), w4.x);
    bin[p1] = pack_rec(s4.y, d4.y & (BUCKET_NODES - 1), w4.y);
    bin[p2] = pack_rec(s4.z, d4.z & (BUCKET_NODES - 1), w4.z);
    bin[p3] = pack_rec(s4.w, d4.w & (BUCKET_NODES - 1), w4.w);
  } else {
    for (; e < E; e++) {
      int d = dst[e];
      int p = atomicAdd(&bcur[d >> BUCKET_SHIFT], 1);
      bin[p] = pack_rec(src[e], d & (BUCKET_NODES - 1), w[e]);
    }
  }
}

// ---------------- phase 2: per-bucket sort into per-node CSR order ---------
__global__ __launch_bounds__(256) void sort_kernel(const unsigned* __restrict__ bin,
                                                   const int* __restrict__ row_ptr,
                                                   int N, unsigned* __restrict__ csr) {
  __shared__ int lcur[BUCKET_NODES];
  int b = blockIdx.x;
  int n0 = b * BUCKET_NODES;
  int n1 = min(n0 + BUCKET_NODES, N);
  int t = threadIdx.x;
  if (t < n1 - n0) lcur[t] = row_ptr[n0 + t];
  __syncthreads();
  int beg = row_ptr[n0];
  int end = row_ptr[n1];
  for (int i = beg + t; i < end; i += 256) {
    unsigned r = bin[i];
    int local = (r >> 17) & (BUCKET_NODES - 1);
    int pos = atomicAdd(&lcur[local], 1);
    csr[pos] = r;   // local bits become don't-care downstream
  }
}

// ---------------- gather SpMM: one wave per destination node ---------------
__global__ __launch_bounds__(256) void spmm_kernel(const unsigned* __restrict__ sup,
                                                   const int* __restrict__ row_ptr,
                                                   const unsigned* __restrict__ csr,
                                                   float* __restrict__ out, int N) {
  int wave = threadIdx.x >> 6;
  int lane = threadIdx.x & 63;
  int node = blockIdx.x * 4 + wave;
  if (node >= N) return;
  int j0 = row_ptr[node];
  int j1 = row_ptr[node + 1];
  float accx = 0.f, accy = 0.f;
  const float wscale = 1.f / 1024.f;
  for (int base = j0; base < j1; base += 64) {
    int cnt = min(64, j1 - base);
    unsigned myrec = 0;
    if (lane < cnt) myrec = csr[base + lane];
    int j = 0;
    for (; j + 8 <= cnt; j += 8) {
      int s[8]; float w[8]; unsigned p[8];
#pragma unroll
      for (int u = 0; u < 8; u++) {
        unsigned r = (unsigned)__builtin_amdgcn_readlane((int)myrec, j + u);
        s[u] = (int)(r & 0x1FFFFu);
        w[u] = (float)(r >> 22) * wscale;
      }
#pragma unroll
      for (int u = 0; u < 8; u++) p[u] = sup[(size_t)s[u] * 64 + lane];
#pragma unroll
      for (int u = 0; u < 8; u++) {
        accx += w[u] * bf_lo(p[u]);
        accy += w[u] * bf_hi(p[u]);
      }
    }
    for (; j < cnt; j++) {
      unsigned r = (unsigned)__builtin_amdgcn_readlane((int)myrec, j);
      int sj = (int)(r & 0x1FFFFu);
      float wj = (float)(r >> 22) * wscale;
      unsigned pj = sup[(size_t)sj * 64 + lane];
      accx += wj * bf_lo(pj);
      accy += wj * bf_hi(pj);
    }
  }
  ((float2*)out)[(size_t)node * 64 + lane] = make_float2(accx, accy);
}

// ---------------- fallback: atomic scatter (small ws) ----------------
__global__ void scatter_kernel(const float* __restrict__ x, const float* __restrict__ W,
                               const int* __restrict__ src, const int* __restrict__ dst,
                               const float* __restrict__ w, long long total,
                               float* __restrict__ out) {
  long long i = (long long)blockIdx.x * blockDim.x + threadIdx.x;
  if (i < total) {
    int e = (int)(i >> 7);
    int c = (int)(i & 127);
    float acc = 0.f;
    const float* xr = &x[(size_t)src[e] * DIN];
    for (int k = 0; k < DIN; k++) acc += xr[k] * W[(size_t)k * DOUT + c];
    atomicAdd(&out[(size_t)dst[e] * DOUT + c], w[e] * acc);
  }
}

extern "C" void kernel_launch(void* const* d_in, const int* in_sizes, int n_in,
                              void* d_out, int out_size, void* d_ws, size_t ws_size,
                              hipStream_t stream) {
  const float* x = (const float*)d_in[0];
  const int* esrc = (const int*)d_in[1];
  const int* edst = (const int*)d_in[2];
  const float* ew = (const float*)d_in[3];
  const float* W = (const float*)d_in[4];
  float* out = (float*)d_out;

  const int N = in_sizes[0] / DIN;   // 100000
  const int E = in_sizes[1];         // 3200000
  const int NB = (N + BUCKET_NODES - 1) / BUCKET_NODES;  // 3125

  char* ws = (char*)d_ws;
  size_t off = 0;
  auto alloc = [&](size_t bytes) {
    size_t o = off;
    off = (off + bytes + 255) & ~(size_t)255;
    return o;
  };
  size_t sup_off = alloc((size_t)N * 64 * 4);       // bf16x2 support table
  size_t rp_off = alloc((size_t)(N + 1) * 4);
  size_t deg_off = alloc((size_t)N * 4);
  size_t tmp_off = alloc((size_t)N * 4);
  size_t bcur_off = alloc((size_t)NB * 4);
  size_t part_off = alloc(128 * 4);
  size_t bin_off = alloc((size_t)E * 4);
  size_t csr_off = alloc((size_t)E * 4);
  bool use_csr = (off <= ws_size);

  unsigned* support = (unsigned*)(ws + sup_off);
  int* row_ptr = (int*)(ws + rp_off);
  int* deg = (int*)(ws + deg_off);
  int* tmp = (int*)(ws + tmp_off);
  int* bcur = (int*)(ws + bcur_off);
  int* partials = (int*)(ws + part_off);
  unsigned* bin = (unsigned*)(ws + bin_off);
  unsigned* csr = (unsigned*)(ws + csr_off);

  if (use_csr) {
    gemm_kernel<<<(N + 63) / 64, 256, 0, stream>>>(x, W, support, N);
    hipMemsetAsync(deg, 0, (size_t)N * 4, stream);
    hist_kernel<<<((E + 3) / 4 + 255) / 256, 256, 0, stream>>>(edst, E, deg);
    int nb = (N + 1023) / 1024;
    scan1_kernel<<<nb, 256, 0, stream>>>(deg, N, tmp, partials);
    scan2_kernel<<<1, 128, 0, stream>>>(partials, nb);
    scan3_kernel<<<(N + 255) / 256, 256, 0, stream>>>(tmp, partials, N, E, row_ptr, bcur);
    bin_kernel<<<((E + 3) / 4 + 255) / 256, 256, 0, stream>>>(esrc, edst, ew, E, bcur, bin);
    sort_kernel<<<NB, 256, 0, stream>>>(bin, row_ptr, N, csr);
    spmm_kernel<<<(N + 3) / 4, 256, 0, stream>>>(support, row_ptr, csr, out, N);
  } else {
    hipMemsetAsync(out, 0, (size_t)N * DOUT * 4, stream);
    long long total = (long long)E * DOUT;
    scatter_kernel<<<(int)((total + 255) / 256), 256, 0, stream>>>(x, W, esrc, edst, ew,
                                                                   total, out);
  }
}

// Round 4
// 544.427 us; speedup vs baseline: 1.4624x; 1.4624x over previous
//
#include <hip/hip_runtime.h>

// GraphConvolution: out = segment_sum_dst( w_e * (x @ W)[src_e] )
// N=100000 nodes, E=3200000 edges, D_IN=256, D_OUT=128, fp32 in/out.
// support stored bf16x2.
// CSR build designed so every written cache line has a single-XCD writer:
//   bin1: LDS counting-sort by super-bucket (1024 nodes), coalesced chunk flush
//   bin2: per-SB local degree count+scan (-> row_ptr) + scatter into own window

#define DIN 256
#define DOUT 128
#define SB_SHIFT 10
#define SB_NODES 1024
#define MAX_NSB 128
#define TILE 4096            // edges per bin1 workgroup
#define SPLIT 2              // bin2 workgroups per super-bucket

struct alignas(8) EdgeRec { int src; float w; };

__device__ __forceinline__ unsigned pack_bf16x2(float a, float b) {
  unsigned ua = __float_as_uint(a);
  unsigned ub = __float_as_uint(b);
  ua += 0x7fffu + ((ua >> 16) & 1u);   // round-to-nearest-even
  ub += 0x7fffu + ((ub >> 16) & 1u);
  return (ua >> 16) | (ub & 0xffff0000u);
}
__device__ __forceinline__ float bf_lo(unsigned p) { return __uint_as_float(p << 16); }
__device__ __forceinline__ float bf_hi(unsigned p) { return __uint_as_float(p & 0xffff0000u); }

// ---------------- GEMM: support = x @ W (fp32 vector ALU, bf16x2 output) ---
__global__ __launch_bounds__(256) void gemm_kernel(const float* __restrict__ x,
                                                   const float* __restrict__ W,
                                                   unsigned* __restrict__ support,
                                                   int M) {
  __shared__ float As[64][33];
  __shared__ float Bs[32][132];
  const int tid = threadIdx.x;
  const int ty = tid >> 4;
  const int tx = tid & 15;
  const int rowBase = blockIdx.x * 64;

  float acc[4][8];
#pragma unroll
  for (int i = 0; i < 4; i++)
#pragma unroll
    for (int j = 0; j < 8; j++) acc[i][j] = 0.f;

  for (int k0 = 0; k0 < DIN; k0 += 32) {
#pragma unroll
    for (int l = 0; l < 2; l++) {
      int f = tid + l * 256;
      int r = f >> 3, c4 = f & 7;
      float4 v = make_float4(0.f, 0.f, 0.f, 0.f);
      int gr = rowBase + r;
      if (gr < M) v = *(const float4*)&x[(size_t)gr * DIN + k0 + c4 * 4];
      As[r][c4 * 4 + 0] = v.x; As[r][c4 * 4 + 1] = v.y;
      As[r][c4 * 4 + 2] = v.z; As[r][c4 * 4 + 3] = v.w;
    }
#pragma unroll
    for (int l = 0; l < 4; l++) {
      int f = tid + l * 256;
      int r = f >> 5, c4 = f & 31;
      float4 v = *(const float4*)&W[(size_t)(k0 + r) * DOUT + c4 * 4];
      *(float4*)&Bs[r][c4 * 4] = v;
    }
    __syncthreads();
#pragma unroll
    for (int kk = 0; kk < 32; kk++) {
      float a[4];
#pragma unroll
      for (int i = 0; i < 4; i++) a[i] = As[ty + i * 16][kk];
      float b[8];
#pragma unroll
      for (int jj = 0; jj < 4; jj++) {
        float2 bb = *(const float2*)&Bs[kk][32 * jj + 2 * tx];
        b[2 * jj] = bb.x; b[2 * jj + 1] = bb.y;
      }
#pragma unroll
      for (int i = 0; i < 4; i++)
#pragma unroll
        for (int j = 0; j < 8; j++) acc[i][j] += a[i] * b[j];
    }
    __syncthreads();
  }
#pragma unroll
  for (int i = 0; i < 4; i++) {
    int gr = rowBase + ty + i * 16;
    if (gr < M) {
#pragma unroll
      for (int jj = 0; jj < 4; jj++)
        support[(size_t)gr * 64 + 16 * jj + tx] =
            pack_bf16x2(acc[i][2 * jj], acc[i][2 * jj + 1]);
    }
  }
}

// ---------------- super-bucket totals (LDS histogram, 98 counters) ---------
__global__ __launch_bounds__(256) void sbhist_kernel(const int* __restrict__ dst, int E,
                                                     int nsb, int* __restrict__ sb_tot) {
  __shared__ int h[MAX_NSB];
  int t = threadIdx.x;
  for (int i = t; i < nsb; i += 256) h[i] = 0;
  __syncthreads();
  int e4 = E >> 2;
  for (int i = blockIdx.x * 256 + t; i < e4; i += gridDim.x * 256) {
    int4 d = *(const int4*)&dst[i * 4];
    atomicAdd(&h[d.x >> SB_SHIFT], 1);
    atomicAdd(&h[d.y >> SB_SHIFT], 1);
    atomicAdd(&h[d.z >> SB_SHIFT], 1);
    atomicAdd(&h[d.w >> SB_SHIFT], 1);
  }
  if (blockIdx.x == 0 && t < (E & 3)) atomicAdd(&h[dst[e4 * 4 + t] >> SB_SHIFT], 1);
  __syncthreads();
  for (int i = t; i < nsb; i += 256)
    if (h[i]) atomicAdd(&sb_tot[i], h[i]);
}

// ---------------- exclusive scan of <=128 SB totals ------------------------
__global__ __launch_bounds__(128) void sbscan_kernel(const int* __restrict__ sb_tot, int nsb,
                                                     int* __restrict__ sb_base,
                                                     int* __restrict__ sb_cur) {
  __shared__ int s[128];
  int t = threadIdx.x;
  int v = (t < nsb) ? sb_tot[t] : 0;
  s[t] = v;
  __syncthreads();
  for (int off = 1; off < 128; off <<= 1) {
    int u = (t >= off) ? s[t - off] : 0;
    __syncthreads();
    s[t] += u;
    __syncthreads();
  }
  if (t < nsb) {
    int excl = s[t] - v;
    sb_base[t] = excl;
    sb_cur[t] = excl;
  }
}

// ---------------- bin1: LDS counting-sort by SB, coalesced chunk flush -----
// record: x = src(17) | local(10)<<17 ; y = fp32 w
__global__ __launch_bounds__(256) void bin1_kernel(const int* __restrict__ src,
                                                   const int* __restrict__ dst,
                                                   const float* __restrict__ w,
                                                   int E, int nsb,
                                                   int* __restrict__ sb_cur,
                                                   uint2* __restrict__ bin) {
  __shared__ uint2 recs[TILE];
  __shared__ unsigned short sbid[TILE];
  __shared__ int hist[MAX_NSB], segstart[MAX_NSB], cursor[MAX_NSB], sbbase[MAX_NSB];
  __shared__ int sc[128];
  int t = threadIdx.x;
  int e0 = blockIdx.x * TILE;
  int cnt = min(TILE, E - e0);

  for (int i = t; i < nsb; i += 256) hist[i] = 0;
  __syncthreads();
  // pass 1: count
  for (int k = 0; k < TILE / 256; k++) {
    int e = e0 + k * 256 + t;
    if (e < E) atomicAdd(&hist[dst[e] >> SB_SHIFT], 1);
  }
  __syncthreads();
  // scan 98 counters (Hillis-Steele over 128)
  if (t < 128) sc[t] = (t < nsb) ? hist[t] : 0;
  __syncthreads();
  for (int off = 1; off < 128; off <<= 1) {
    int v = 0;
    if (t < 128 && t >= off) v = sc[t - off];
    __syncthreads();
    if (t < 128) sc[t] += v;
    __syncthreads();
  }
  if (t < nsb) {
    int c = hist[t];
    int excl = sc[t] - c;
    segstart[t] = excl;
    cursor[t] = excl;
    if (c > 0) sbbase[t] = atomicAdd(&sb_cur[t], c);  // reserve global chunk
  }
  __syncthreads();
  // pass 2: place records grouped by SB in LDS
  for (int k = 0; k < TILE / 256; k++) {
    int e = e0 + k * 256 + t;
    if (e < E) {
      int d = dst[e];
      int sb = d >> SB_SHIFT;
      int slot = atomicAdd(&cursor[sb], 1);
      recs[slot] = make_uint2((unsigned)src[e] | ((unsigned)(d & (SB_NODES - 1)) << 17),
                              __float_as_uint(w[e]));
      sbid[slot] = (unsigned short)sb;
    }
  }
  __syncthreads();
  // flush: consecutive LDS slots -> consecutive global addrs within segments
  for (int k = 0; k < TILE / 256; k++) {
    int slot = k * 256 + t;
    if (slot < cnt) {
      int sb = sbid[slot];
      bin[sbbase[sb] + (slot - segstart[sb])] = recs[slot];
    }
  }
}

// ---------------- bin2: per-SB degree count + scan + scatter ---------------
// grid = nsb*SPLIT. Writes row_ptr (q==0) and node-ordered CSR (own window).
__global__ __launch_bounds__(256) void bin2_kernel(const uint2* __restrict__ bin,
                                                   const int* __restrict__ sb_base,
                                                   const int* __restrict__ sb_cur,
                                                   int N, int E,
                                                   int* __restrict__ row_ptr,
                                                   EdgeRec* __restrict__ csr) {
  __shared__ int lhist[SB_NODES];
  __shared__ int part[256];
  int t = threadIdx.x;
  int sb = blockIdx.x / SPLIT;
  int q = blockIdx.x % SPLIT;
  int nodeBase = sb * SB_NODES;
  int beg = sb_base[sb];
  int end = sb_cur[sb];     // after bin1, cur == base + total

  for (int i = t; i < SB_NODES; i += 256) lhist[i] = 0;
  __syncthreads();
  // count local degrees over the whole SB
  for (int i = beg + t; i < end; i += 256) {
    uint2 r = bin[i];
    atomicAdd(&lhist[(r.x >> 17) & (SB_NODES - 1)], 1);
  }
  __syncthreads();
  // scan 1024 counters: thread owns 4, then scan 256 partials
  int a0 = lhist[4 * t], a1 = lhist[4 * t + 1], a2 = lhist[4 * t + 2], a3 = lhist[4 * t + 3];
  int tsum = a0 + a1 + a2 + a3;
  part[t] = tsum;
  __syncthreads();
  for (int off = 1; off < 256; off <<= 1) {
    int v = (t >= off) ? part[t - off] : 0;
    __syncthreads();
    part[t] += v;
    __syncthreads();
  }
  int excl = part[t] - tsum;
  lhist[4 * t] = excl;
  lhist[4 * t + 1] = excl + a0;
  lhist[4 * t + 2] = excl + a0 + a1;
  lhist[4 * t + 3] = excl + a0 + a1 + a2;
  __syncthreads();
  // q==0 publishes row_ptr for this SB (before cursors are perturbed... only
  // our own quarter's cursors get perturbed after this barrier, and we write
  // row_ptr now, so values are intact)
  if (q == 0) {
    for (int l = t; l < SB_NODES; l += 256) {
      int node = nodeBase + l;
      if (node < N) row_ptr[node] = beg + lhist[l];
    }
    if (t == 0 && nodeBase + SB_NODES >= N) row_ptr[N] = E;
  }
  __syncthreads();
  // scatter own local-range records into the CSR window
  int lo = q * (SB_NODES / SPLIT);
  int hi = lo + (SB_NODES / SPLIT);
  for (int i = beg + t; i < end; i += 256) {
    uint2 r = bin[i];
    int local = (int)((r.x >> 17) & (SB_NODES - 1));
    if (local >= lo && local < hi) {
      int pos = beg + atomicAdd(&lhist[local], 1);
      EdgeRec er;
      er.src = (int)(r.x & 0x1FFFFu);
      er.w = __uint_as_float(r.y);
      csr[pos] = er;
    }
  }
}

// ---------------- gather SpMM: one wave per destination node ---------------
__global__ __launch_bounds__(256) void spmm_kernel(const unsigned* __restrict__ sup,
                                                   const int* __restrict__ row_ptr,
                                                   const EdgeRec* __restrict__ csr,
                                                   float* __restrict__ out, int N) {
  int wave = threadIdx.x >> 6;
  int lane = threadIdx.x & 63;
  int node = blockIdx.x * 4 + wave;
  if (node >= N) return;
  int j0 = row_ptr[node];
  int j1 = row_ptr[node + 1];
  float accx = 0.f, accy = 0.f;
  for (int base = j0; base < j1; base += 64) {
    int cnt = min(64, j1 - base);
    int mysrc = 0, myw = 0;
    if (lane < cnt) {
      EdgeRec r = csr[base + lane];
      mysrc = r.src;
      myw = __float_as_int(r.w);
    }
    int j = 0;
    for (; j + 8 <= cnt; j += 8) {
      int s[8]; float w[8]; unsigned p[8];
#pragma unroll
      for (int u = 0; u < 8; u++) {
        s[u] = __builtin_amdgcn_readlane(mysrc, j + u);
        w[u] = __int_as_float(__builtin_amdgcn_readlane(myw, j + u));
      }
#pragma unroll
      for (int u = 0; u < 8; u++) p[u] = sup[(size_t)s[u] * 64 + lane];
#pragma unroll
      for (int u = 0; u < 8; u++) {
        accx += w[u] * bf_lo(p[u]);
        accy += w[u] * bf_hi(p[u]);
      }
    }
    for (; j < cnt; j++) {
      int sj = __builtin_amdgcn_readlane(mysrc, j);
      float wj = __int_as_float(__builtin_amdgcn_readlane(myw, j));
      unsigned pj = sup[(size_t)sj * 64 + lane];
      accx += wj * bf_lo(pj);
      accy += wj * bf_hi(pj);
    }
  }
  ((float2*)out)[(size_t)node * 64 + lane] = make_float2(accx, accy);
}

// ---------------- fallback: atomic scatter (small ws) ----------------
__global__ void scatter_kernel(const float* __restrict__ x, const float* __restrict__ W,
                               const int* __restrict__ src, const int* __restrict__ dst,
                               const float* __restrict__ w, long long total,
                               float* __restrict__ out) {
  long long i = (long long)blockIdx.x * blockDim.x + threadIdx.x;
  if (i < total) {
    int e = (int)(i >> 7);
    int c = (int)(i & 127);
    float acc = 0.f;
    const float* xr = &x[(size_t)src[e] * DIN];
    for (int k = 0; k < DIN; k++) acc += xr[k] * W[(size_t)k * DOUT + c];
    atomicAdd(&out[(size_t)dst[e] * DOUT + c], w[e] * acc);
  }
}

extern "C" void kernel_launch(void* const* d_in, const int* in_sizes, int n_in,
                              void* d_out, int out_size, void* d_ws, size_t ws_size,
                              hipStream_t stream) {
  const float* x = (const float*)d_in[0];
  const int* esrc = (const int*)d_in[1];
  const int* edst = (const int*)d_in[2];
  const float* ew = (const float*)d_in[3];
  const float* W = (const float*)d_in[4];
  float* out = (float*)d_out;

  const int N = in_sizes[0] / DIN;   // 100000
  const int E = in_sizes[1];         // 3200000
  const int nsb = (N + SB_NODES - 1) / SB_NODES;  // 98

  char* ws = (char*)d_ws;
  size_t off = 0;
  auto alloc = [&](size_t bytes) {
    size_t o = off;
    off = (off + bytes + 255) & ~(size_t)255;
    return o;
  };
  size_t sup_off = alloc((size_t)N * 64 * 4);       // bf16x2 support table
  size_t rp_off = alloc((size_t)(N + 1) * 4);
  size_t sbt_off = alloc(MAX_NSB * 4);
  size_t sbb_off = alloc(MAX_NSB * 4);
  size_t sbc_off = alloc(MAX_NSB * 4);
  size_t bin_off = alloc((size_t)E * 8);
  size_t csr_off = alloc((size_t)E * 8);
  bool use_csr = (off <= ws_size);

  unsigned* support = (unsigned*)(ws + sup_off);
  int* row_ptr = (int*)(ws + rp_off);
  int* sb_tot = (int*)(ws + sbt_off);
  int* sb_base = (int*)(ws + sbb_off);
  int* sb_cur = (int*)(ws + sbc_off);
  uint2* bin = (uint2*)(ws + bin_off);
  EdgeRec* csr = (EdgeRec*)(ws + csr_off);

  if (use_csr) {
    gemm_kernel<<<(N + 63) / 64, 256, 0, stream>>>(x, W, support, N);
    hipMemsetAsync(sb_tot, 0, MAX_NSB * 4, stream);
    sbhist_kernel<<<512, 256, 0, stream>>>(edst, E, nsb, sb_tot);
    sbscan_kernel<<<1, 128, 0, stream>>>(sb_tot, nsb, sb_base, sb_cur);
    bin1_kernel<<<(E + TILE - 1) / TILE, 256, 0, stream>>>(esrc, edst, ew, E, nsb,
                                                           sb_cur, bin);
    bin2_kernel<<<nsb * SPLIT, 256, 0, stream>>>(bin, sb_base, sb_cur, N, E,
                                                 row_ptr, csr);
    spmm_kernel<<<(N + 3) / 4, 256, 0, stream>>>(support, row_ptr, csr, out, N);
  } else {
    hipMemsetAsync(out, 0, (size_t)N * DOUT * 4, stream);
    long long total = (long long)E * DOUT;
    scatter_kernel<<<(int)((total + 255) / 256), 256, 0, stream>>>(x, W, esrc, edst, ew,
                                                                   total, out);
  }
}

// Round 5
// 486.825 us; speedup vs baseline: 1.6355x; 1.1183x over previous
//
#include <hip/hip_runtime.h>

// GraphConvolution: out = segment_sum_dst( w_e * (x @ W)[src_e] )
// N=100000 nodes, E=3200000 edges, D_IN=256, D_OUT=128, fp32 in/out.
// support stored bf16 row-major [N][128] (spmm reads bf16x2 pairs).
// GEMM: bf16 MFMA 16x16x32, LDS-free (A from global fp32 + in-reg cvt,
//       B from pre-transposed bf16 Wt[n][k], one dwordx4 per fragment).
// CSR build: single-XCD-writer two-phase scatter (bin1 LDS sort, bin2 window).

#define DIN 256
#define DOUT 128
#define SB_SHIFT 10
#define SB_NODES 1024
#define MAX_NSB 128
#define TILE 4096
#define SPLIT 2

struct alignas(8) EdgeRec { int src; float w; };

typedef __attribute__((ext_vector_type(8))) short bf16x8;
typedef __attribute__((ext_vector_type(4))) float f32x4;

__device__ __forceinline__ unsigned pack_bf16x2(float a, float b) {
  unsigned ua = __float_as_uint(a);
  unsigned ub = __float_as_uint(b);
  ua += 0x7fffu + ((ua >> 16) & 1u);   // round-to-nearest-even
  ub += 0x7fffu + ((ub >> 16) & 1u);
  return (ua >> 16) | (ub & 0xffff0000u);
}
__device__ __forceinline__ unsigned short bf16_rne(float a) {
  unsigned ua = __float_as_uint(a);
  ua += 0x7fffu + ((ua >> 16) & 1u);
  return (unsigned short)(ua >> 16);
}
__device__ __forceinline__ float bf_lo(unsigned p) { return __uint_as_float(p << 16); }
__device__ __forceinline__ float bf_hi(unsigned p) { return __uint_as_float(p & 0xffff0000u); }

// ---------------- W transpose: W[256][128] fp32 -> Wt[128][256] bf16 -------
__global__ __launch_bounds__(256) void wtrans_kernel(const float* __restrict__ W,
                                                     unsigned short* __restrict__ Wt) {
  __shared__ float s[64][65];
  int t = threadIdx.x;
  int kt = blockIdx.x >> 1;      // 0..3 (k chunks of 64)
  int nt = blockIdx.x & 1;       // 0..1 (n chunks of 64)
#pragma unroll
  for (int i = 0; i < 16; i++) {
    int idx = i * 256 + t;
    int kk = idx >> 6, nn = idx & 63;
    s[kk][nn] = W[(size_t)(kt * 64 + kk) * DOUT + nt * 64 + nn];
  }
  __syncthreads();
#pragma unroll
  for (int i = 0; i < 16; i++) {
    int idx = i * 256 + t;
    int nn = idx >> 6, kk = idx & 63;
    Wt[(size_t)(nt * 64 + nn) * DIN + kt * 64 + kk] = bf16_rne(s[kk][nn]);
  }
}

// ---------------- GEMM: support = x @ W via bf16 MFMA, no LDS --------------
// Block tile 128x128, 4 waves in 2x2. Wave tile 64x64 = 4x4 MFMA 16x16 tiles.
// A-frag: x[row=base+rt*16+(lane&15)][k0+(lane>>4)*8+j], fp32->bf16 in-reg.
// B-frag: Wt[col][k] -> one 16B load per fragment.
// C store: col=lane&15, row=(lane>>4)*4+reg (m89-verified layout).
__global__ __launch_bounds__(256) void gemm_mfma_kernel(const float* __restrict__ x,
                                                        const unsigned short* __restrict__ Wt,
                                                        unsigned short* __restrict__ support,
                                                        int M) {
  const int lane = threadIdx.x & 63;
  const int wave = threadIdx.x >> 6;
  const int wr = wave >> 1, wc = wave & 1;
  const int m = lane & 15, kg = lane >> 4;
  const int rowBase = blockIdx.x * 128 + wr * 64;

  f32x4 acc[4][4];
#pragma unroll
  for (int rt = 0; rt < 4; rt++)
#pragma unroll
    for (int ct = 0; ct < 4; ct++) acc[rt][ct] = (f32x4)(0.f);

  const float* arow[4];
#pragma unroll
  for (int rt = 0; rt < 4; rt++) {
    int r = rowBase + rt * 16 + m;
    if (r > M - 1) r = M - 1;              // clamp: tail rows read row M-1
    arow[rt] = x + (size_t)r * DIN + kg * 8;
  }
  const unsigned short* brow[4];
#pragma unroll
  for (int ct = 0; ct < 4; ct++)
    brow[ct] = Wt + (size_t)(wc * 64 + ct * 16 + m) * DIN + kg * 8;

#pragma unroll 2
  for (int k0 = 0; k0 < DIN; k0 += 32) {
    bf16x8 af[4], bfr[4];
#pragma unroll
    for (int rt = 0; rt < 4; rt++) {
      float4 a0 = *(const float4*)(arow[rt] + k0);
      float4 a1 = *(const float4*)(arow[rt] + k0 + 4);
      union { bf16x8 f; unsigned u[4]; } ua;
      ua.u[0] = pack_bf16x2(a0.x, a0.y);
      ua.u[1] = pack_bf16x2(a0.z, a0.w);
      ua.u[2] = pack_bf16x2(a1.x, a1.y);
      ua.u[3] = pack_bf16x2(a1.z, a1.w);
      af[rt] = ua.f;
    }
#pragma unroll
    for (int ct = 0; ct < 4; ct++) {
      union { bf16x8 f; uint4 u; } ub;
      ub.u = *(const uint4*)(brow[ct] + k0);
      bfr[ct] = ub.f;
    }
#pragma unroll
    for (int rt = 0; rt < 4; rt++)
#pragma unroll
      for (int ct = 0; ct < 4; ct++)
        acc[rt][ct] = __builtin_amdgcn_mfma_f32_16x16x32_bf16(af[rt], bfr[ct],
                                                              acc[rt][ct], 0, 0, 0);
  }

#pragma unroll
  for (int rt = 0; rt < 4; rt++) {
#pragma unroll
    for (int r = 0; r < 4; r++) {
      int row = rowBase + rt * 16 + kg * 4 + r;
      if (row < M) {
#pragma unroll
        for (int ct = 0; ct < 4; ct++) {
          int col = wc * 64 + ct * 16 + m;
          support[(size_t)row * DOUT + col] = bf16_rne(acc[rt][ct][r]);
        }
      }
    }
  }
}

// ---------------- super-bucket totals (LDS histogram, 98 counters) ---------
__global__ __launch_bounds__(256) void sbhist_kernel(const int* __restrict__ dst, int E,
                                                     int nsb, int* __restrict__ sb_tot) {
  __shared__ int h[MAX_NSB];
  int t = threadIdx.x;
  for (int i = t; i < nsb; i += 256) h[i] = 0;
  __syncthreads();
  int e4 = E >> 2;
  for (int i = blockIdx.x * 256 + t; i < e4; i += gridDim.x * 256) {
    int4 d = *(const int4*)&dst[i * 4];
    atomicAdd(&h[d.x >> SB_SHIFT], 1);
    atomicAdd(&h[d.y >> SB_SHIFT], 1);
    atomicAdd(&h[d.z >> SB_SHIFT], 1);
    atomicAdd(&h[d.w >> SB_SHIFT], 1);
  }
  if (blockIdx.x == 0 && t < (E & 3)) atomicAdd(&h[dst[e4 * 4 + t] >> SB_SHIFT], 1);
  __syncthreads();
  for (int i = t; i < nsb; i += 256)
    if (h[i]) atomicAdd(&sb_tot[i], h[i]);
}

// ---------------- exclusive scan of <=128 SB totals ------------------------
__global__ __launch_bounds__(128) void sbscan_kernel(const int* __restrict__ sb_tot, int nsb,
                                                     int* __restrict__ sb_base,
                                                     int* __restrict__ sb_cur) {
  __shared__ int s[128];
  int t = threadIdx.x;
  int v = (t < nsb) ? sb_tot[t] : 0;
  s[t] = v;
  __syncthreads();
  for (int off = 1; off < 128; off <<= 1) {
    int u = (t >= off) ? s[t - off] : 0;
    __syncthreads();
    s[t] += u;
    __syncthreads();
  }
  if (t < nsb) {
    int excl = s[t] - v;
    sb_base[t] = excl;
    sb_cur[t] = excl;
  }
}

// ---------------- bin1: LDS counting-sort by SB, coalesced chunk flush -----
__global__ __launch_bounds__(256) void bin1_kernel(const int* __restrict__ src,
                                                   const int* __restrict__ dst,
                                                   const float* __restrict__ w,
                                                   int E, int nsb,
                                                   int* __restrict__ sb_cur,
                                                   uint2* __restrict__ bin) {
  __shared__ uint2 recs[TILE];
  __shared__ unsigned short sbid[TILE];
  __shared__ int hist[MAX_NSB], segstart[MAX_NSB], cursor[MAX_NSB], sbbase[MAX_NSB];
  __shared__ int sc[128];
  int t = threadIdx.x;
  int e0 = blockIdx.x * TILE;
  int cnt = min(TILE, E - e0);

  for (int i = t; i < nsb; i += 256) hist[i] = 0;
  __syncthreads();
  for (int k = 0; k < TILE / 256; k++) {
    int e = e0 + k * 256 + t;
    if (e < E) atomicAdd(&hist[dst[e] >> SB_SHIFT], 1);
  }
  __syncthreads();
  if (t < 128) sc[t] = (t < nsb) ? hist[t] : 0;
  __syncthreads();
  for (int off = 1; off < 128; off <<= 1) {
    int v = 0;
    if (t < 128 && t >= off) v = sc[t - off];
    __syncthreads();
    if (t < 128) sc[t] += v;
    __syncthreads();
  }
  if (t < nsb) {
    int c = hist[t];
    int excl = sc[t] - c;
    segstart[t] = excl;
    cursor[t] = excl;
    if (c > 0) sbbase[t] = atomicAdd(&sb_cur[t], c);
  }
  __syncthreads();
  for (int k = 0; k < TILE / 256; k++) {
    int e = e0 + k * 256 + t;
    if (e < E) {
      int d = dst[e];
      int sb = d >> SB_SHIFT;
      int slot = atomicAdd(&cursor[sb], 1);
      recs[slot] = make_uint2((unsigned)src[e] | ((unsigned)(d & (SB_NODES - 1)) << 17),
                              __float_as_uint(w[e]));
      sbid[slot] = (unsigned short)sb;
    }
  }
  __syncthreads();
  for (int k = 0; k < TILE / 256; k++) {
    int slot = k * 256 + t;
    if (slot < cnt) {
      int sb = sbid[slot];
      bin[sbbase[sb] + (slot - segstart[sb])] = recs[slot];
    }
  }
}

// ---------------- bin2: per-SB degree count + scan + scatter ---------------
__global__ __launch_bounds__(256) void bin2_kernel(const uint2* __restrict__ bin,
                                                   const int* __restrict__ sb_base,
                                                   const int* __restrict__ sb_cur,
                                                   int N, int E,
                                                   int* __restrict__ row_ptr,
                                                   EdgeRec* __restrict__ csr) {
  __shared__ int lhist[SB_NODES];
  __shared__ int part[256];
  int t = threadIdx.x;
  int sb = blockIdx.x / SPLIT;
  int q = blockIdx.x % SPLIT;
  int nodeBase = sb * SB_NODES;
  int beg = sb_base[sb];
  int end = sb_cur[sb];

  for (int i = t; i < SB_NODES; i += 256) lhist[i] = 0;
  __syncthreads();
  for (int i = beg + t; i < end; i += 256) {
    uint2 r = bin[i];
    atomicAdd(&lhist[(r.x >> 17) & (SB_NODES - 1)], 1);
  }
  __syncthreads();
  int a0 = lhist[4 * t], a1 = lhist[4 * t + 1], a2 = lhist[4 * t + 2], a3 = lhist[4 * t + 3];
  int tsum = a0 + a1 + a2 + a3;
  part[t] = tsum;
  __syncthreads();
  for (int off = 1; off < 256; off <<= 1) {
    int v = (t >= off) ? part[t - off] : 0;
    __syncthreads();
    part[t] += v;
    __syncthreads();
  }
  int excl = part[t] - tsum;
  lhist[4 * t] = excl;
  lhist[4 * t + 1] = excl + a0;
  lhist[4 * t + 2] = excl + a0 + a1;
  lhist[4 * t + 3] = excl + a0 + a1 + a2;
  __syncthreads();
  if (q == 0) {
    for (int l = t; l < SB_NODES; l += 256) {
      int node = nodeBase + l;
      if (node < N) row_ptr[node] = beg + lhist[l];
    }
    if (t == 0 && nodeBase + SB_NODES >= N) row_ptr[N] = E;
  }
  __syncthreads();
  int lo = q * (SB_NODES / SPLIT);
  int hi = lo + (SB_NODES / SPLIT);
  for (int i = beg + t; i < end; i += 256) {
    uint2 r = bin[i];
    int local = (int)((r.x >> 17) & (SB_NODES - 1));
    if (local >= lo && local < hi) {
      int pos = beg + atomicAdd(&lhist[local], 1);
      EdgeRec er;
      er.src = (int)(r.x & 0x1FFFFu);
      er.w = __uint_as_float(r.y);
      csr[pos] = er;
    }
  }
}

// ---------------- gather SpMM: one wave per destination node ---------------
__global__ __launch_bounds__(256) void spmm_kernel(const unsigned* __restrict__ sup,
                                                   const int* __restrict__ row_ptr,
                                                   const EdgeRec* __restrict__ csr,
                                                   float* __restrict__ out, int N) {
  int wave = threadIdx.x >> 6;
  int lane = threadIdx.x & 63;
  int node = blockIdx.x * 4 + wave;
  if (node >= N) return;
  int j0 = row_ptr[node];
  int j1 = row_ptr[node + 1];
  float accx = 0.f, accy = 0.f;
  for (int base = j0; base < j1; base += 64) {
    int cnt = min(64, j1 - base);
    int mysrc = 0, myw = 0;
    if (lane < cnt) {
      EdgeRec r = csr[base + lane];
      mysrc = r.src;
      myw = __float_as_int(r.w);
    }
    int j = 0;
    for (; j + 8 <= cnt; j += 8) {
      int s[8]; float w[8]; unsigned p[8];
#pragma unroll
      for (int u = 0; u < 8; u++) {
        s[u] = __builtin_amdgcn_readlane(mysrc, j + u);
        w[u] = __int_as_float(__builtin_amdgcn_readlane(myw, j + u));
      }
#pragma unroll
      for (int u = 0; u < 8; u++) p[u] = sup[(size_t)s[u] * 64 + lane];
#pragma unroll
      for (int u = 0; u < 8; u++) {
        accx += w[u] * bf_lo(p[u]);
        accy += w[u] * bf_hi(p[u]);
      }
    }
    for (; j < cnt; j++) {
      int sj = __builtin_amdgcn_readlane(mysrc, j);
      float wj = __int_as_float(__builtin_amdgcn_readlane(myw, j));
      unsigned pj = sup[(size_t)sj * 64 + lane];
      accx += wj * bf_lo(pj);
      accy += wj * bf_hi(pj);
    }
  }
  ((float2*)out)[(size_t)node * 64 + lane] = make_float2(accx, accy);
}

// ---------------- fallback: atomic scatter (small ws) ----------------
__global__ void scatter_kernel(const float* __restrict__ x, const float* __restrict__ W,
                               const int* __restrict__ src, const int* __restrict__ dst,
                               const float* __restrict__ w, long long total,
                               float* __restrict__ out) {
  long long i = (long long)blockIdx.x * blockDim.x + threadIdx.x;
  if (i < total) {
    int e = (int)(i >> 7);
    int c = (int)(i & 127);
    float acc = 0.f;
    const float* xr = &x[(size_t)src[e] * DIN];
    for (int k = 0; k < DIN; k++) acc += xr[k] * W[(size_t)k * DOUT + c];
    atomicAdd(&out[(size_t)dst[e] * DOUT + c], w[e] * acc);
  }
}

extern "C" void kernel_launch(void* const* d_in, const int* in_sizes, int n_in,
                              void* d_out, int out_size, void* d_ws, size_t ws_size,
                              hipStream_t stream) {
  const float* x = (const float*)d_in[0];
  const int* esrc = (const int*)d_in[1];
  const int* edst = (const int*)d_in[2];
  const float* ew = (const float*)d_in[3];
  const float* W = (const float*)d_in[4];
  float* out = (float*)d_out;

  const int N = in_sizes[0] / DIN;   // 100000
  const int E = in_sizes[1];         // 3200000
  const int nsb = (N + SB_NODES - 1) / SB_NODES;  // 98

  char* ws = (char*)d_ws;
  size_t off = 0;
  auto alloc = [&](size_t bytes) {
    size_t o = off;
    off = (off + bytes + 255) & ~(size_t)255;
    return o;
  };
  size_t sup_off = alloc((size_t)N * DOUT * 2);     // bf16 support table
  size_t wt_off = alloc((size_t)DOUT * DIN * 2);    // bf16 W^T
  size_t rp_off = alloc((size_t)(N + 1) * 4);
  size_t sbt_off = alloc(MAX_NSB * 4);
  size_t sbb_off = alloc(MAX_NSB * 4);
  size_t sbc_off = alloc(MAX_NSB * 4);
  size_t bin_off = alloc((size_t)E * 8);
  size_t csr_off = alloc((size_t)E * 8);
  bool use_csr = (off <= ws_size);

  unsigned short* support = (unsigned short*)(ws + sup_off);
  unsigned short* Wt = (unsigned short*)(ws + wt_off);
  int* row_ptr = (int*)(ws + rp_off);
  int* sb_tot = (int*)(ws + sbt_off);
  int* sb_base = (int*)(ws + sbb_off);
  int* sb_cur = (int*)(ws + sbc_off);
  uint2* bin = (uint2*)(ws + bin_off);
  EdgeRec* csr = (EdgeRec*)(ws + csr_off);

  if (use_csr) {
    wtrans_kernel<<<8, 256, 0, stream>>>(W, Wt);
    gemm_mfma_kernel<<<(N + 127) / 128, 256, 0, stream>>>(x, Wt, support, N);
    hipMemsetAsync(sb_tot, 0, MAX_NSB * 4, stream);
    sbhist_kernel<<<512, 256, 0, stream>>>(edst, E, nsb, sb_tot);
    sbscan_kernel<<<1, 128, 0, stream>>>(sb_tot, nsb, sb_base, sb_cur);
    bin1_kernel<<<(E + TILE - 1) / TILE, 256, 0, stream>>>(esrc, edst, ew, E, nsb,
                                                           sb_cur, bin);
    bin2_kernel<<<nsb * SPLIT, 256, 0, stream>>>(bin, sb_base, sb_cur, N, E,
                                                 row_ptr, csr);
    spmm_kernel<<<(N + 3) / 4, 256, 0, stream>>>((const unsigned*)support, row_ptr, csr,
                                                 out, N);
  } else {
    hipMemsetAsync(out, 0, (size_t)N * DOUT * 4, stream);
    long long total = (long long)E * DOUT;
    scatter_kernel<<<(int)((total + 255) / 256), 256, 0, stream>>>(x, W, esrc, edst, ew,
                                                                   total, out);
  }
}

// Round 6
// 485.480 us; speedup vs baseline: 1.6400x; 1.0028x over previous
//
#include <hip/hip_runtime.h>

// GraphConvolution: out = segment_sum_dst( w_e * (x @ W)[src_e] )
// N=100000 nodes, E=3200000 edges, D_IN=256, D_OUT=128, fp32 in/out.
// support stored bf16 row-major [N][128].
// GEMM: bf16 MFMA 16x16x32, LDS-free, row-split waves (x read exactly once).
// SpMM: wave = 4 edge-groups x 16 col-lanes; one VMEM inst gathers 4 rows (1KB).
// CSR build: single-XCD-writer two-phase scatter (bin1 LDS sort, bin2 window).

#define DIN 256
#define DOUT 128
#define SB_SHIFT 10
#define SB_NODES 1024
#define MAX_NSB 128
#define TILE 4096
#define SPLIT 2

struct alignas(8) EdgeRec { int src; float w; };

typedef __attribute__((ext_vector_type(8))) short bf16x8;
typedef __attribute__((ext_vector_type(4))) float f32x4;

__device__ __forceinline__ unsigned pack_bf16x2(float a, float b) {
  unsigned ua = __float_as_uint(a);
  unsigned ub = __float_as_uint(b);
  ua += 0x7fffu + ((ua >> 16) & 1u);   // round-to-nearest-even
  ub += 0x7fffu + ((ub >> 16) & 1u);
  return (ua >> 16) | (ub & 0xffff0000u);
}
__device__ __forceinline__ unsigned short bf16_rne(float a) {
  unsigned ua = __float_as_uint(a);
  ua += 0x7fffu + ((ua >> 16) & 1u);
  return (unsigned short)(ua >> 16);
}
__device__ __forceinline__ float bf_lo(unsigned p) { return __uint_as_float(p << 16); }
__device__ __forceinline__ float bf_hi(unsigned p) { return __uint_as_float(p & 0xffff0000u); }

// ---------------- W transpose: W[256][128] fp32 -> Wt[128][256] bf16 -------
__global__ __launch_bounds__(256) void wtrans_kernel(const float* __restrict__ W,
                                                     unsigned short* __restrict__ Wt) {
  __shared__ float s[64][65];
  int t = threadIdx.x;
  int kt = blockIdx.x >> 1;
  int nt = blockIdx.x & 1;
#pragma unroll
  for (int i = 0; i < 16; i++) {
    int idx = i * 256 + t;
    int kk = idx >> 6, nn = idx & 63;
    s[kk][nn] = W[(size_t)(kt * 64 + kk) * DOUT + nt * 64 + nn];
  }
  __syncthreads();
#pragma unroll
  for (int i = 0; i < 16; i++) {
    int idx = i * 256 + t;
    int nn = idx >> 6, kk = idx & 63;
    Wt[(size_t)(nt * 64 + nn) * DIN + kt * 64 + kk] = bf16_rne(s[kk][nn]);
  }
}

// ---------------- GEMM: support = x @ W via bf16 MFMA, no LDS --------------
// Block tile 128 rows; 4 waves row-split (32 rows each) x full 128 cols.
// Per wave: 2 row-tiles x 8 col-tiles of 16x16x32 MFMA. x read exactly once.
__global__ __launch_bounds__(256) void gemm_mfma_kernel(const float* __restrict__ x,
                                                        const unsigned short* __restrict__ Wt,
                                                        unsigned short* __restrict__ support,
                                                        int M) {
  const int lane = threadIdx.x & 63;
  const int wave = threadIdx.x >> 6;
  const int m = lane & 15, kg = lane >> 4;
  const int rowBase = blockIdx.x * 128 + wave * 32;

  f32x4 acc[2][8];
#pragma unroll
  for (int rt = 0; rt < 2; rt++)
#pragma unroll
    for (int ct = 0; ct < 8; ct++) acc[rt][ct] = (f32x4)(0.f);

  const float* arow[2];
#pragma unroll
  for (int rt = 0; rt < 2; rt++) {
    int r = rowBase + rt * 16 + m;
    if (r > M - 1) r = M - 1;
    arow[rt] = x + (size_t)r * DIN + kg * 8;
  }
  const unsigned short* brow[8];
#pragma unroll
  for (int ct = 0; ct < 8; ct++)
    brow[ct] = Wt + (size_t)(ct * 16 + m) * DIN + kg * 8;

#pragma unroll 2
  for (int k0 = 0; k0 < DIN; k0 += 32) {
    bf16x8 af[2], bfr[8];
#pragma unroll
    for (int rt = 0; rt < 2; rt++) {
      float4 a0 = *(const float4*)(arow[rt] + k0);
      float4 a1 = *(const float4*)(arow[rt] + k0 + 4);
      union { bf16x8 f; unsigned u[4]; } ua;
      ua.u[0] = pack_bf16x2(a0.x, a0.y);
      ua.u[1] = pack_bf16x2(a0.z, a0.w);
      ua.u[2] = pack_bf16x2(a1.x, a1.y);
      ua.u[3] = pack_bf16x2(a1.z, a1.w);
      af[rt] = ua.f;
    }
#pragma unroll
    for (int ct = 0; ct < 8; ct++) {
      union { bf16x8 f; uint4 u; } ub;
      ub.u = *(const uint4*)(brow[ct] + k0);
      bfr[ct] = ub.f;
    }
#pragma unroll
    for (int rt = 0; rt < 2; rt++)
#pragma unroll
      for (int ct = 0; ct < 8; ct++)
        acc[rt][ct] = __builtin_amdgcn_mfma_f32_16x16x32_bf16(af[rt], bfr[ct],
                                                              acc[rt][ct], 0, 0, 0);
  }

#pragma unroll
  for (int rt = 0; rt < 2; rt++) {
#pragma unroll
    for (int r = 0; r < 4; r++) {
      int row = rowBase + rt * 16 + kg * 4 + r;
      if (row < M) {
#pragma unroll
        for (int ct = 0; ct < 8; ct++) {
          int col = ct * 16 + m;
          support[(size_t)row * DOUT + col] = bf16_rne(acc[rt][ct][r]);
        }
      }
    }
  }
}

// ---------------- super-bucket totals (LDS histogram, 98 counters) ---------
__global__ __launch_bounds__(256) void sbhist_kernel(const int* __restrict__ dst, int E,
                                                     int nsb, int* __restrict__ sb_tot) {
  __shared__ int h[MAX_NSB];
  int t = threadIdx.x;
  for (int i = t; i < nsb; i += 256) h[i] = 0;
  __syncthreads();
  int e4 = E >> 2;
  for (int i = blockIdx.x * 256 + t; i < e4; i += gridDim.x * 256) {
    int4 d = *(const int4*)&dst[i * 4];
    atomicAdd(&h[d.x >> SB_SHIFT], 1);
    atomicAdd(&h[d.y >> SB_SHIFT], 1);
    atomicAdd(&h[d.z >> SB_SHIFT], 1);
    atomicAdd(&h[d.w >> SB_SHIFT], 1);
  }
  if (blockIdx.x == 0 && t < (E & 3)) atomicAdd(&h[dst[e4 * 4 + t] >> SB_SHIFT], 1);
  __syncthreads();
  for (int i = t; i < nsb; i += 256)
    if (h[i]) atomicAdd(&sb_tot[i], h[i]);
}

// ---------------- exclusive scan of <=128 SB totals ------------------------
__global__ __launch_bounds__(128) void sbscan_kernel(const int* __restrict__ sb_tot, int nsb,
                                                     int* __restrict__ sb_base,
                                                     int* __restrict__ sb_cur) {
  __shared__ int s[128];
  int t = threadIdx.x;
  int v = (t < nsb) ? sb_tot[t] : 0;
  s[t] = v;
  __syncthreads();
  for (int off = 1; off < 128; off <<= 1) {
    int u = (t >= off) ? s[t - off] : 0;
    __syncthreads();
    s[t] += u;
    __syncthreads();
  }
  if (t < nsb) {
    int excl = s[t] - v;
    sb_base[t] = excl;
    sb_cur[t] = excl;
  }
}

// ---------------- bin1: LDS counting-sort by SB, coalesced chunk flush -----
__global__ __launch_bounds__(256) void bin1_kernel(const int* __restrict__ src,
                                                   const int* __restrict__ dst,
                                                   const float* __restrict__ w,
                                                   int E, int nsb,
                                                   int* __restrict__ sb_cur,
                                                   uint2* __restrict__ bin) {
  __shared__ uint2 recs[TILE];
  __shared__ unsigned short sbid[TILE];
  __shared__ int hist[MAX_NSB], segstart[MAX_NSB], cursor[MAX_NSB], sbbase[MAX_NSB];
  __shared__ int sc[128];
  int t = threadIdx.x;
  int e0 = blockIdx.x * TILE;
  int cnt = min(TILE, E - e0);

  for (int i = t; i < nsb; i += 256) hist[i] = 0;
  __syncthreads();
  for (int k = 0; k < TILE / 256; k++) {
    int e = e0 + k * 256 + t;
    if (e < E) atomicAdd(&hist[dst[e] >> SB_SHIFT], 1);
  }
  __syncthreads();
  if (t < 128) sc[t] = (t < nsb) ? hist[t] : 0;
  __syncthreads();
  for (int off = 1; off < 128; off <<= 1) {
    int v = 0;
    if (t < 128 && t >= off) v = sc[t - off];
    __syncthreads();
    if (t < 128) sc[t] += v;
    __syncthreads();
  }
  if (t < nsb) {
    int c = hist[t];
    int excl = sc[t] - c;
    segstart[t] = excl;
    cursor[t] = excl;
    if (c > 0) sbbase[t] = atomicAdd(&sb_cur[t], c);
  }
  __syncthreads();
  for (int k = 0; k < TILE / 256; k++) {
    int e = e0 + k * 256 + t;
    if (e < E) {
      int d = dst[e];
      int sb = d >> SB_SHIFT;
      int slot = atomicAdd(&cursor[sb], 1);
      recs[slot] = make_uint2((unsigned)src[e] | ((unsigned)(d & (SB_NODES - 1)) << 17),
                              __float_as_uint(w[e]));
      sbid[slot] = (unsigned short)sb;
    }
  }
  __syncthreads();
  for (int k = 0; k < TILE / 256; k++) {
    int slot = k * 256 + t;
    if (slot < cnt) {
      int sb = sbid[slot];
      bin[sbbase[sb] + (slot - segstart[sb])] = recs[slot];
    }
  }
}

// ---------------- bin2: per-SB degree count + scan + scatter ---------------
__global__ __launch_bounds__(256) void bin2_kernel(const uint2* __restrict__ bin,
                                                   const int* __restrict__ sb_base,
                                                   const int* __restrict__ sb_cur,
                                                   int N, int E,
                                                   int* __restrict__ row_ptr,
                                                   EdgeRec* __restrict__ csr) {
  __shared__ int lhist[SB_NODES];
  __shared__ int part[256];
  int t = threadIdx.x;
  int sb = blockIdx.x / SPLIT;
  int q = blockIdx.x % SPLIT;
  int nodeBase = sb * SB_NODES;
  int beg = sb_base[sb];
  int end = sb_cur[sb];

  for (int i = t; i < SB_NODES; i += 256) lhist[i] = 0;
  __syncthreads();
  for (int i = beg + t; i < end; i += 256) {
    uint2 r = bin[i];
    atomicAdd(&lhist[(r.x >> 17) & (SB_NODES - 1)], 1);
  }
  __syncthreads();
  int a0 = lhist[4 * t], a1 = lhist[4 * t + 1], a2 = lhist[4 * t + 2], a3 = lhist[4 * t + 3];
  int tsum = a0 + a1 + a2 + a3;
  part[t] = tsum;
  __syncthreads();
  for (int off = 1; off < 256; off <<= 1) {
    int v = (t >= off) ? part[t - off] : 0;
    __syncthreads();
    part[t] += v;
    __syncthreads();
  }
  int excl = part[t] - tsum;
  lhist[4 * t] = excl;
  lhist[4 * t + 1] = excl + a0;
  lhist[4 * t + 2] = excl + a0 + a1;
  lhist[4 * t + 3] = excl + a0 + a1 + a2;
  __syncthreads();
  if (q == 0) {
    for (int l = t; l < SB_NODES; l += 256) {
      int node = nodeBase + l;
      if (node < N) row_ptr[node] = beg + lhist[l];
    }
    if (t == 0 && nodeBase + SB_NODES >= N) row_ptr[N] = E;
  }
  __syncthreads();
  int lo = q * (SB_NODES / SPLIT);
  int hi = lo + (SB_NODES / SPLIT);
  for (int i = beg + t; i < end; i += 256) {
    uint2 r = bin[i];
    int local = (int)((r.x >> 17) & (SB_NODES - 1));
    if (local >= lo && local < hi) {
      int pos = beg + atomicAdd(&lhist[local], 1);
      EdgeRec er;
      er.src = (int)(r.x & 0x1FFFFu);
      er.w = __uint_as_float(r.y);
      csr[pos] = er;
    }
  }
}

// ---------------- gather SpMM v2: wave = 4 edge-groups x 16 col-lanes ------
// One VMEM inst gathers 4 different support rows (4 x 256B = 1KB); unroll 4
// puts 16 edges / 4KB in flight per wave. Cross-group combine via shfl_xor.
__global__ __launch_bounds__(256) void spmm_kernel(const unsigned* __restrict__ sup,
                                                   const int* __restrict__ row_ptr,
                                                   const EdgeRec* __restrict__ csr,
                                                   float* __restrict__ out, int N) {
  int wave = threadIdx.x >> 6;
  int lane = threadIdx.x & 63;
  int g = lane >> 4;        // edge subgroup 0..3
  int c = lane & 15;        // col chunk: uints c*4..c*4+3 (cols c*8..c*8+7)
  int node = blockIdx.x * 4 + wave;
  if (node >= N) return;
  int j0 = row_ptr[node];
  int j1 = row_ptr[node + 1];
  float acc[8];
#pragma unroll
  for (int i = 0; i < 8; i++) acc[i] = 0.f;

  for (int base = j0; base < j1; base += 64) {
    int cnt = min(64, j1 - base);
    int mysrc = 0;
    float myw = 0.f;
    if (lane < cnt) {
      EdgeRec r = csr[base + lane];
      mysrc = r.src;
      myw = r.w;
    }
    for (int j = 0; j < cnt; j += 16) {
      uint4 p[4];
      float wv[4];
#pragma unroll
      for (int u = 0; u < 4; u++) {
        int e = j + 4 * u + g;
        int jj = min(e, cnt - 1);
        int s = __shfl(mysrc, jj, 64);
        float ww = __shfl(myw, jj, 64);
        wv[u] = (e < cnt) ? ww : 0.f;
        p[u] = *(const uint4*)(sup + (size_t)s * 64 + c * 4);
      }
#pragma unroll
      for (int u = 0; u < 4; u++) {
        unsigned pv0 = p[u].x, pv1 = p[u].y, pv2 = p[u].z, pv3 = p[u].w;
        acc[0] += wv[u] * bf_lo(pv0);
        acc[1] += wv[u] * bf_hi(pv0);
        acc[2] += wv[u] * bf_lo(pv1);
        acc[3] += wv[u] * bf_hi(pv1);
        acc[4] += wv[u] * bf_lo(pv2);
        acc[5] += wv[u] * bf_hi(pv2);
        acc[6] += wv[u] * bf_lo(pv3);
        acc[7] += wv[u] * bf_hi(pv3);
      }
    }
  }
#pragma unroll
  for (int i = 0; i < 8; i++) {
    acc[i] += __shfl_xor(acc[i], 16, 64);
    acc[i] += __shfl_xor(acc[i], 32, 64);
  }
  if (g == 0) {
    float* orow = out + (size_t)node * DOUT + c * 8;
    *(float4*)orow = make_float4(acc[0], acc[1], acc[2], acc[3]);
    *(float4*)(orow + 4) = make_float4(acc[4], acc[5], acc[6], acc[7]);
  }
}

// ---------------- fallback: atomic scatter (small ws) ----------------
__global__ void scatter_kernel(const float* __restrict__ x, const float* __restrict__ W,
                               const int* __restrict__ src, const int* __restrict__ dst,
                               const float* __restrict__ w, long long total,
                               float* __restrict__ out) {
  long long i = (long long)blockIdx.x * blockDim.x + threadIdx.x;
  if (i < total) {
    int e = (int)(i >> 7);
    int c = (int)(i & 127);
    float acc = 0.f;
    const float* xr = &x[(size_t)src[e] * DIN];
    for (int k = 0; k < DIN; k++) acc += xr[k] * W[(size_t)k * DOUT + c];
    atomicAdd(&out[(size_t)dst[e] * DOUT + c], w[e] * acc);
  }
}

extern "C" void kernel_launch(void* const* d_in, const int* in_sizes, int n_in,
                              void* d_out, int out_size, void* d_ws, size_t ws_size,
                              hipStream_t stream) {
  const float* x = (const float*)d_in[0];
  const int* esrc = (const int*)d_in[1];
  const int* edst = (const int*)d_in[2];
  const float* ew = (const float*)d_in[3];
  const float* W = (const float*)d_in[4];
  float* out = (float*)d_out;

  const int N = in_sizes[0] / DIN;   // 100000
  const int E = in_sizes[1];         // 3200000
  const int nsb = (N + SB_NODES - 1) / SB_NODES;  // 98

  char* ws = (char*)d_ws;
  size_t off = 0;
  auto alloc = [&](size_t bytes) {
    size_t o = off;
    off = (off + bytes + 255) & ~(size_t)255;
    return o;
  };
  size_t sup_off = alloc((size_t)N * DOUT * 2);     // bf16 support table
  size_t wt_off = alloc((size_t)DOUT * DIN * 2);    // bf16 W^T
  size_t rp_off = alloc((size_t)(N + 1) * 4);
  size_t sbt_off = alloc(MAX_NSB * 4);
  size_t sbb_off = alloc(MAX_NSB * 4);
  size_t sbc_off = alloc(MAX_NSB * 4);
  size_t bin_off = alloc((size_t)E * 8);
  size_t csr_off = alloc((size_t)E * 8);
  bool use_csr = (off <= ws_size);

  unsigned short* support = (unsigned short*)(ws + sup_off);
  unsigned short* Wt = (unsigned short*)(ws + wt_off);
  int* row_ptr = (int*)(ws + rp_off);
  int* sb_tot = (int*)(ws + sbt_off);
  int* sb_base = (int*)(ws + sbb_off);
  int* sb_cur = (int*)(ws + sbc_off);
  uint2* bin = (uint2*)(ws + bin_off);
  EdgeRec* csr = (EdgeRec*)(ws + csr_off);

  if (use_csr) {
    wtrans_kernel<<<8, 256, 0, stream>>>(W, Wt);
    gemm_mfma_kernel<<<(N + 127) / 128, 256, 0, stream>>>(x, Wt, support, N);
    hipMemsetAsync(sb_tot, 0, MAX_NSB * 4, stream);
    sbhist_kernel<<<512, 256, 0, stream>>>(edst, E, nsb, sb_tot);
    sbscan_kernel<<<1, 128, 0, stream>>>(sb_tot, nsb, sb_base, sb_cur);
    bin1_kernel<<<(E + TILE - 1) / TILE, 256, 0, stream>>>(esrc, edst, ew, E, nsb,
                                                           sb_cur, bin);
    bin2_kernel<<<nsb * SPLIT, 256, 0, stream>>>(bin, sb_base, sb_cur, N, E,
                                                 row_ptr, csr);
    spmm_kernel<<<(N + 3) / 4, 256, 0, stream>>>((const unsigned*)support, row_ptr, csr,
                                                 out, N);
  } else {
    hipMemsetAsync(out, 0, (size_t)N * DOUT * 4, stream);
    long long total = (long long)E * DOUT;
    scatter_kernel<<<(int)((total + 255) / 256), 256, 0, stream>>>(x, W, esrc, edst, ew,
                                                                   total, out);
  }
}

// Round 7
// 475.123 us; speedup vs baseline: 1.6758x; 1.0218x over previous
//
#include <hip/hip_runtime.h>

// GraphConvolution: out = segment_sum_dst( w_e * (x @ W)[src_e] )
// N=100000 nodes, E=3200000 edges, D_IN=256, D_OUT=128, fp32 in/out.
// support stored bf16 row-major [N][128].
// GEMM: bf16 MFMA 16x16x32, LDS-free, row-split waves (x read exactly once).
// SpMM: TWO sequential column-half passes (12.8MB gather footprint each ->
//       higher per-XCD L2 hit rate); CSR recs 4B (src17|w15 fixed-point).
// CSR build: single-XCD-writer two-phase scatter (bin1 LDS sort, bin2 window).

#define DIN 256
#define DOUT 128
#define SB_SHIFT 10
#define SB_NODES 1024
#define MAX_NSB 128
#define TILE 4096
#define SPLIT 2

__device__ __forceinline__ unsigned pack_bf16x2(float a, float b) {
  unsigned ua = __float_as_uint(a);
  unsigned ub = __float_as_uint(b);
  ua += 0x7fffu + ((ua >> 16) & 1u);   // round-to-nearest-even
  ub += 0x7fffu + ((ub >> 16) & 1u);
  return (ua >> 16) | (ub & 0xffff0000u);
}
__device__ __forceinline__ unsigned short bf16_rne(float a) {
  unsigned ua = __float_as_uint(a);
  ua += 0x7fffu + ((ua >> 16) & 1u);
  return (unsigned short)(ua >> 16);
}
__device__ __forceinline__ float bf_lo(unsigned p) { return __uint_as_float(p << 16); }
__device__ __forceinline__ float bf_hi(unsigned p) { return __uint_as_float(p & 0xffff0000u); }

typedef __attribute__((ext_vector_type(8))) short bf16x8;
typedef __attribute__((ext_vector_type(4))) float f32x4;

// ---------------- W transpose: W[256][128] fp32 -> Wt[128][256] bf16 -------
__global__ __launch_bounds__(256) void wtrans_kernel(const float* __restrict__ W,
                                                     unsigned short* __restrict__ Wt) {
  __shared__ float s[64][65];
  int t = threadIdx.x;
  int kt = blockIdx.x >> 1;
  int nt = blockIdx.x & 1;
#pragma unroll
  for (int i = 0; i < 16; i++) {
    int idx = i * 256 + t;
    int kk = idx >> 6, nn = idx & 63;
    s[kk][nn] = W[(size_t)(kt * 64 + kk) * DOUT + nt * 64 + nn];
  }
  __syncthreads();
#pragma unroll
  for (int i = 0; i < 16; i++) {
    int idx = i * 256 + t;
    int nn = idx >> 6, kk = idx & 63;
    Wt[(size_t)(nt * 64 + nn) * DIN + kt * 64 + kk] = bf16_rne(s[kk][nn]);
  }
}

// ---------------- GEMM: support = x @ W via bf16 MFMA, no LDS --------------
__global__ __launch_bounds__(256) void gemm_mfma_kernel(const float* __restrict__ x,
                                                        const unsigned short* __restrict__ Wt,
                                                        unsigned short* __restrict__ support,
                                                        int M) {
  const int lane = threadIdx.x & 63;
  const int wave = threadIdx.x >> 6;
  const int m = lane & 15, kg = lane >> 4;
  const int rowBase = blockIdx.x * 128 + wave * 32;

  f32x4 acc[2][8];
#pragma unroll
  for (int rt = 0; rt < 2; rt++)
#pragma unroll
    for (int ct = 0; ct < 8; ct++) acc[rt][ct] = (f32x4)(0.f);

  const float* arow[2];
#pragma unroll
  for (int rt = 0; rt < 2; rt++) {
    int r = rowBase + rt * 16 + m;
    if (r > M - 1) r = M - 1;
    arow[rt] = x + (size_t)r * DIN + kg * 8;
  }
  const unsigned short* brow[8];
#pragma unroll
  for (int ct = 0; ct < 8; ct++)
    brow[ct] = Wt + (size_t)(ct * 16 + m) * DIN + kg * 8;

#pragma unroll 2
  for (int k0 = 0; k0 < DIN; k0 += 32) {
    bf16x8 af[2], bfr[8];
#pragma unroll
    for (int rt = 0; rt < 2; rt++) {
      float4 a0 = *(const float4*)(arow[rt] + k0);
      float4 a1 = *(const float4*)(arow[rt] + k0 + 4);
      union { bf16x8 f; unsigned u[4]; } ua;
      ua.u[0] = pack_bf16x2(a0.x, a0.y);
      ua.u[1] = pack_bf16x2(a0.z, a0.w);
      ua.u[2] = pack_bf16x2(a1.x, a1.y);
      ua.u[3] = pack_bf16x2(a1.z, a1.w);
      af[rt] = ua.f;
    }
#pragma unroll
    for (int ct = 0; ct < 8; ct++) {
      union { bf16x8 f; uint4 u; } ub;
      ub.u = *(const uint4*)(brow[ct] + k0);
      bfr[ct] = ub.f;
    }
#pragma unroll
    for (int rt = 0; rt < 2; rt++)
#pragma unroll
      for (int ct = 0; ct < 8; ct++)
        acc[rt][ct] = __builtin_amdgcn_mfma_f32_16x16x32_bf16(af[rt], bfr[ct],
                                                              acc[rt][ct], 0, 0, 0);
  }

#pragma unroll
  for (int rt = 0; rt < 2; rt++) {
#pragma unroll
    for (int r = 0; r < 4; r++) {
      int row = rowBase + rt * 16 + kg * 4 + r;
      if (row < M) {
#pragma unroll
        for (int ct = 0; ct < 8; ct++) {
          int col = ct * 16 + m;
          support[(size_t)row * DOUT + col] = bf16_rne(acc[rt][ct][r]);
        }
      }
    }
  }
}

// ---------------- super-bucket totals (LDS histogram, 98 counters) ---------
__global__ __launch_bounds__(256) void sbhist_kernel(const int* __restrict__ dst, int E,
                                                     int nsb, int* __restrict__ sb_tot) {
  __shared__ int h[MAX_NSB];
  int t = threadIdx.x;
  for (int i = t; i < nsb; i += 256) h[i] = 0;
  __syncthreads();
  int e4 = E >> 2;
  for (int i = blockIdx.x * 256 + t; i < e4; i += gridDim.x * 256) {
    int4 d = *(const int4*)&dst[i * 4];
    atomicAdd(&h[d.x >> SB_SHIFT], 1);
    atomicAdd(&h[d.y >> SB_SHIFT], 1);
    atomicAdd(&h[d.z >> SB_SHIFT], 1);
    atomicAdd(&h[d.w >> SB_SHIFT], 1);
  }
  if (blockIdx.x == 0 && t < (E & 3)) atomicAdd(&h[dst[e4 * 4 + t] >> SB_SHIFT], 1);
  __syncthreads();
  for (int i = t; i < nsb; i += 256)
    if (h[i]) atomicAdd(&sb_tot[i], h[i]);
}

// ---------------- exclusive scan of <=128 SB totals ------------------------
__global__ __launch_bounds__(128) void sbscan_kernel(const int* __restrict__ sb_tot, int nsb,
                                                     int* __restrict__ sb_base,
                                                     int* __restrict__ sb_cur) {
  __shared__ int s[128];
  int t = threadIdx.x;
  int v = (t < nsb) ? sb_tot[t] : 0;
  s[t] = v;
  __syncthreads();
  for (int off = 1; off < 128; off <<= 1) {
    int u = (t >= off) ? s[t - off] : 0;
    __syncthreads();
    s[t] += u;
    __syncthreads();
  }
  if (t < nsb) {
    int excl = s[t] - v;
    sb_base[t] = excl;
    sb_cur[t] = excl;
  }
}

// ---------------- bin1: LDS counting-sort by SB, coalesced chunk flush -----
__global__ __launch_bounds__(256) void bin1_kernel(const int* __restrict__ src,
                                                   const int* __restrict__ dst,
                                                   const float* __restrict__ w,
                                                   int E, int nsb,
                                                   int* __restrict__ sb_cur,
                                                   uint2* __restrict__ bin) {
  __shared__ uint2 recs[TILE];
  __shared__ unsigned short sbid[TILE];
  __shared__ int hist[MAX_NSB], segstart[MAX_NSB], cursor[MAX_NSB], sbbase[MAX_NSB];
  __shared__ int sc[128];
  int t = threadIdx.x;
  int e0 = blockIdx.x * TILE;
  int cnt = min(TILE, E - e0);

  for (int i = t; i < nsb; i += 256) hist[i] = 0;
  __syncthreads();
  for (int k = 0; k < TILE / 256; k++) {
    int e = e0 + k * 256 + t;
    if (e < E) atomicAdd(&hist[dst[e] >> SB_SHIFT], 1);
  }
  __syncthreads();
  if (t < 128) sc[t] = (t < nsb) ? hist[t] : 0;
  __syncthreads();
  for (int off = 1; off < 128; off <<= 1) {
    int v = 0;
    if (t < 128 && t >= off) v = sc[t - off];
    __syncthreads();
    if (t < 128) sc[t] += v;
    __syncthreads();
  }
  if (t < nsb) {
    int c = hist[t];
    int excl = sc[t] - c;
    segstart[t] = excl;
    cursor[t] = excl;
    if (c > 0) sbbase[t] = atomicAdd(&sb_cur[t], c);
  }
  __syncthreads();
  for (int k = 0; k < TILE / 256; k++) {
    int e = e0 + k * 256 + t;
    if (e < E) {
      int d = dst[e];
      int sb = d >> SB_SHIFT;
      int slot = atomicAdd(&cursor[sb], 1);
      recs[slot] = make_uint2((unsigned)src[e] | ((unsigned)(d & (SB_NODES - 1)) << 17),
                              __float_as_uint(w[e]));
      sbid[slot] = (unsigned short)sb;
    }
  }
  __syncthreads();
  for (int k = 0; k < TILE / 256; k++) {
    int slot = k * 256 + t;
    if (slot < cnt) {
      int sb = sbid[slot];
      bin[sbbase[sb] + (slot - segstart[sb])] = recs[slot];
    }
  }
}

// ---------------- bin2: per-SB degree count + scan + scatter ---------------
// Emits 4B CSR recs: src(17) | wq(15)<<17, wq = round(w*32767).
__global__ __launch_bounds__(256) void bin2_kernel(const uint2* __restrict__ bin,
                                                   const int* __restrict__ sb_base,
                                                   const int* __restrict__ sb_cur,
                                                   int N, int E,
                                                   int* __restrict__ row_ptr,
                                                   unsigned* __restrict__ csr) {
  __shared__ int lhist[SB_NODES];
  __shared__ int part[256];
  int t = threadIdx.x;
  int sb = blockIdx.x / SPLIT;
  int q = blockIdx.x % SPLIT;
  int nodeBase = sb * SB_NODES;
  int beg = sb_base[sb];
  int end = sb_cur[sb];

  for (int i = t; i < SB_NODES; i += 256) lhist[i] = 0;
  __syncthreads();
  for (int i = beg + t; i < end; i += 256) {
    uint2 r = bin[i];
    atomicAdd(&lhist[(r.x >> 17) & (SB_NODES - 1)], 1);
  }
  __syncthreads();
  int a0 = lhist[4 * t], a1 = lhist[4 * t + 1], a2 = lhist[4 * t + 2], a3 = lhist[4 * t + 3];
  int tsum = a0 + a1 + a2 + a3;
  part[t] = tsum;
  __syncthreads();
  for (int off = 1; off < 256; off <<= 1) {
    int v = (t >= off) ? part[t - off] : 0;
    __syncthreads();
    part[t] += v;
    __syncthreads();
  }
  int excl = part[t] - tsum;
  lhist[4 * t] = excl;
  lhist[4 * t + 1] = excl + a0;
  lhist[4 * t + 2] = excl + a0 + a1;
  lhist[4 * t + 3] = excl + a0 + a1 + a2;
  __syncthreads();
  if (q == 0) {
    for (int l = t; l < SB_NODES; l += 256) {
      int node = nodeBase + l;
      if (node < N) row_ptr[node] = beg + lhist[l];
    }
    if (t == 0 && nodeBase + SB_NODES >= N) row_ptr[N] = E;
  }
  __syncthreads();
  int lo = q * (SB_NODES / SPLIT);
  int hi = lo + (SB_NODES / SPLIT);
  for (int i = beg + t; i < end; i += 256) {
    uint2 r = bin[i];
    int local = (int)((r.x >> 17) & (SB_NODES - 1));
    if (local >= lo && local < hi) {
      int pos = beg + atomicAdd(&lhist[local], 1);
      float wf = __uint_as_float(r.y);
      unsigned wq = (unsigned)(wf * 32767.f + 0.5f);
      if (wq > 32767u) wq = 32767u;
      csr[pos] = (r.x & 0x1FFFFu) | (wq << 17);
    }
  }
}

// ---------------- gather SpMM v3: column-half pass, wave per node ----------
// pass p gathers only 128B (cols p*64..p*64+63) per edge -> 12.8MB footprint.
// wave = 4 edge-groups x 16 col-lanes; lane loads uint2 (4 cols).
__global__ __launch_bounds__(256) void spmm_kernel(const unsigned* __restrict__ sup,
                                                   const int* __restrict__ row_ptr,
                                                   const unsigned* __restrict__ csr,
                                                   float* __restrict__ out, int N,
                                                   int pass) {
  int wave = threadIdx.x >> 6;
  int lane = threadIdx.x & 63;
  int g = lane >> 4;        // edge subgroup 0..3
  int c = lane & 15;        // col chunk: uint2 -> cols pass*64 + c*4 ..+3
  int node = blockIdx.x * 4 + wave;
  if (node >= N) return;
  int j0 = row_ptr[node];
  int j1 = row_ptr[node + 1];
  const unsigned* supb = sup + pass * 32 + c * 2;
  float acc[4] = {0.f, 0.f, 0.f, 0.f};
  const float wscale = 1.f / 32767.f;

  for (int base = j0; base < j1; base += 64) {
    int cnt = min(64, j1 - base);
    unsigned myrec = 0;
    if (lane < cnt) myrec = csr[base + lane];
    for (int j = 0; j < cnt; j += 16) {
      uint2 p[4];
      float wv[4];
#pragma unroll
      for (int u = 0; u < 4; u++) {
        int e = j + 4 * u + g;
        int jj = min(e, cnt - 1);
        unsigned r = (unsigned)__shfl((int)myrec, jj, 64);
        int s = (int)(r & 0x1FFFFu);
        float ww = (float)(r >> 17) * wscale;
        wv[u] = (e < cnt) ? ww : 0.f;
        p[u] = *(const uint2*)(supb + (size_t)s * 64);
      }
#pragma unroll
      for (int u = 0; u < 4; u++) {
        acc[0] += wv[u] * bf_lo(p[u].x);
        acc[1] += wv[u] * bf_hi(p[u].x);
        acc[2] += wv[u] * bf_lo(p[u].y);
        acc[3] += wv[u] * bf_hi(p[u].y);
      }
    }
  }
#pragma unroll
  for (int i = 0; i < 4; i++) {
    acc[i] += __shfl_xor(acc[i], 16, 64);
    acc[i] += __shfl_xor(acc[i], 32, 64);
  }
  if (g == 0) {
    float* orow = out + (size_t)node * DOUT + pass * 64 + c * 4;
    *(float4*)orow = make_float4(acc[0], acc[1], acc[2], acc[3]);
  }
}

// ---------------- fallback: atomic scatter (small ws) ----------------
__global__ void scatter_kernel(const float* __restrict__ x, const float* __restrict__ W,
                               const int* __restrict__ src, const int* __restrict__ dst,
                               const float* __restrict__ w, long long total,
                               float* __restrict__ out) {
  long long i = (long long)blockIdx.x * blockDim.x + threadIdx.x;
  if (i < total) {
    int e = (int)(i >> 7);
    int c = (int)(i & 127);
    float acc = 0.f;
    const float* xr = &x[(size_t)src[e] * DIN];
    for (int k = 0; k < DIN; k++) acc += xr[k] * W[(size_t)k * DOUT + c];
    atomicAdd(&out[(size_t)dst[e] * DOUT + c], w[e] * acc);
  }
}

extern "C" void kernel_launch(void* const* d_in, const int* in_sizes, int n_in,
                              void* d_out, int out_size, void* d_ws, size_t ws_size,
                              hipStream_t stream) {
  const float* x = (const float*)d_in[0];
  const int* esrc = (const int*)d_in[1];
  const int* edst = (const int*)d_in[2];
  const float* ew = (const float*)d_in[3];
  const float* W = (const float*)d_in[4];
  float* out = (float*)d_out;

  const int N = in_sizes[0] / DIN;   // 100000
  const int E = in_sizes[1];         // 3200000
  const int nsb = (N + SB_NODES - 1) / SB_NODES;  // 98

  char* ws = (char*)d_ws;
  size_t off = 0;
  auto alloc = [&](size_t bytes) {
    size_t o = off;
    off = (off + bytes + 255) & ~(size_t)255;
    return o;
  };
  size_t sup_off = alloc((size_t)N * DOUT * 2);     // bf16 support table
  size_t wt_off = alloc((size_t)DOUT * DIN * 2);    // bf16 W^T
  size_t rp_off = alloc((size_t)(N + 1) * 4);
  size_t sbt_off = alloc(MAX_NSB * 4);
  size_t sbb_off = alloc(MAX_NSB * 4);
  size_t sbc_off = alloc(MAX_NSB * 4);
  size_t bin_off = alloc((size_t)E * 8);
  size_t csr_off = alloc((size_t)E * 4);
  bool use_csr = (off <= ws_size);

  unsigned short* support = (unsigned short*)(ws + sup_off);
  unsigned short* Wt = (unsigned short*)(ws + wt_off);
  int* row_ptr = (int*)(ws + rp_off);
  int* sb_tot = (int*)(ws + sbt_off);
  int* sb_base = (int*)(ws + sbb_off);
  int* sb_cur = (int*)(ws + sbc_off);
  uint2* bin = (uint2*)(ws + bin_off);
  unsigned* csr = (unsigned*)(ws + csr_off);

  if (use_csr) {
    wtrans_kernel<<<8, 256, 0, stream>>>(W, Wt);
    gemm_mfma_kernel<<<(N + 127) / 128, 256, 0, stream>>>(x, Wt, support, N);
    hipMemsetAsync(sb_tot, 0, MAX_NSB * 4, stream);
    sbhist_kernel<<<512, 256, 0, stream>>>(edst, E, nsb, sb_tot);
    sbscan_kernel<<<1, 128, 0, stream>>>(sb_tot, nsb, sb_base, sb_cur);
    bin1_kernel<<<(E + TILE - 1) / TILE, 256, 0, stream>>>(esrc, edst, ew, E, nsb,
                                                           sb_cur, bin);
    bin2_kernel<<<nsb * SPLIT, 256, 0, stream>>>(bin, sb_base, sb_cur, N, E,
                                                 row_ptr, csr);
    spmm_kernel<<<(N + 3) / 4, 256, 0, stream>>>((const unsigned*)support, row_ptr, csr,
                                                 out, N, 0);
    spmm_kernel<<<(N + 3) / 4, 256, 0, stream>>>((const unsigned*)support, row_ptr, csr,
                                                 out, N, 1);
  } else {
    hipMemsetAsync(out, 0, (size_t)N * DOUT * 4, stream);
    long long total = (long long)E * DOUT;
    scatter_kernel<<<(int)((total + 255) / 256), 256, 0, stream>>>(x, W, esrc, edst, ew,
                                                                   total, out);
  }
}